// Round 16
// baseline (42.365 us; speedup 1.0000x reference)
//
#include <hip/hip_runtime.h>

// PSROI pooling: fsam (N=8, C=245, H=80, W=80) f32, box (R=8192, 5) f32
// out (R, 245) f32. out[r, c] = mean over fsam[b, c, hs:he, ws:we].
//
// ARITHMETIC (frozen since R10, DO NOT TOUCH): bin = roi * fl32(1/7)
// (reciprocal multiply, 0x3E124925) and edges = SEPARATELY-rounded
// g*bin + off (asm barriers). Matches ref (absmax <= 0.016 << 0.0725).
//
// R16: kill pool-phase box traffic + bucket barriers.
//  - bucket kernel packs per-ROI metadata ONCE (rintf etc. done 1x per ROI
//    instead of 245x): uint2 {r; x1|y1<<8|mw<<16|mh<<24}. Decode is
//    bit-exact vs frozen path ((float)int == rintf value; mw?(float)mw:0.1f
//    == fmaxf(x2-x1,0.1f) for integer-valued f32). Pool's 4 scattered box
//    loads + rintf chain -> one coalesced 8B load.
//  - bucket scan: 64-lane __shfl_up inclusive scan + 4-word LDS exchange
//    (1 barrier, was 32).
//  - fused prefetches its 4 pool entries under the SAT scans.

#define N_ 8
#define C_ 245
#define H_ 80
#define W_ 80
#define R_ 8192
#define P_ 7
#define SROW 84                    // row stride in floats (21 float4)

// XLA-style separately-rounded a*b + c in f32; barriers forbid contraction.
__device__ __forceinline__ float sep_ma(float a, float b, float c) {
    float p = a * b;                 // v_mul_f32, IEEE RN
    asm volatile("" : "+v"(p));      // contraction barrier
    float s = p + c;                 // v_add_f32, IEEE RN
    asm volatile("" : "+v"(s));
    return s;
}

// ---- kernel 1: bucket + metadata pack (8 blocks, 1 barrier) ----
__global__ __launch_bounds__(256) void bucket_kernel(
    const float* __restrict__ box, int* __restrict__ cnt,
    uint2* __restrict__ buckets)
{
    __shared__ int wtot[4];
    int b = blockIdx.x;                    // image
    int t = threadIdx.x;
    int r0 = t * 32;                       // contiguous ROI range per thread

    unsigned match = 0u;
    int m = 0;
    #pragma unroll
    for (int k = 0; k < 32; ++k) {
        int bb = (int)box[(size_t)(r0 + k) * 5];
        if (bb == b) { match |= 1u << k; ++m; }
    }

    // wave-level inclusive scan of m (64 lanes), then cross-wave via LDS
    int lane = t & 63, wid = t >> 6;
    int incl = m;
    #pragma unroll
    for (int d = 1; d < 64; d <<= 1) {
        int v = __shfl_up(incl, d);
        if (lane >= d) incl += v;
    }
    if (lane == 63) wtot[wid] = incl;
    __syncthreads();
    int wpref = 0;
    #pragma unroll
    for (int w = 0; w < 4; ++w) wpref += (w < wid) ? wtot[w] : 0;
    int pos = wpref + incl - m;            // exclusive prefix for this thread

    for (int k = 0; k < 32; ++k) {
        if (match & (1u << k)) {
            int r = r0 + k;
            const float* bx = box + (size_t)r * 5;
            float x1f = rintf(bx[1]);              // np.round half-even
            float y1f = rintf(bx[2]);
            float x2f = rintf(bx[3] + 1.0f);
            float y2f = rintf(bx[4] + 1.0f);
            int x1i = (int)x1f, y1i = (int)y1f;
            int mw  = (int)(x2f - x1f);            // exact small ints
            int mh  = (int)(y2f - y1f);
            mw = mw < 0 ? 0 : (mw > 255 ? 255 : mw);
            mh = mh < 0 ? 0 : (mh > 255 ? 255 : mh);
            uint2 e;
            e.x = (unsigned)r;
            e.y = (unsigned)x1i | ((unsigned)y1i << 8)
                | ((unsigned)mw << 16) | ((unsigned)mh << 24);
            buckets[(size_t)b * R_ + pos++] = e;
        }
    }
    if (t == 255) cnt[b] = wpref + incl;
}

__device__ __forceinline__ float4 f4_add(float4 a, float4 b) {
    return make_float4(a.x + b.x, a.y + b.y, a.z + b.z, a.w + b.w);
}

// ---- kernel 2: fused SAT-in-LDS + pool ----
__global__ __launch_bounds__(256) void fused_kernel(
    const float* __restrict__ fsam,
    const int* __restrict__ cnt,
    const uint2* __restrict__ buckets,
    float* __restrict__ out)
{
    __shared__ float S[H_ * SROW];         // 26880 B, rows 16B-aligned
    int id  = blockIdx.x;                  // 0..1959
    int b   = id & 7;                      // image (XCD swizzle: XCD = b)
    int c   = id >> 3;                     // channel 0..244
    int tid = threadIdx.x;

    const float* plane = fsam + ((size_t)b * C_ + c) * (H_ * W_);

    // ---- load: 1600 float4, coalesced global -> b128 LDS ----
    for (int i = tid; i < 1600; i += 256) {
        int row = (int)((unsigned)i / 20u);
        int c4  = i - row * 20;
        float4 v = ((const float4*)plane)[i];
        ((float4*)S)[row * 21 + c4] = v;
    }

    // ---- prefetch pool metadata (hides L2 latency under the scans) ----
    int n = cnt[b];
    const uint2* lst = buckets + (size_t)b * R_;
    uint2 pe0 = make_uint2(0u, 0u), pe1 = pe0, pe2 = pe0, pe3 = pe0;
    if (tid        < n) pe0 = lst[tid];
    if (tid +  256 < n) pe1 = lst[tid + 256];
    if (tid +  512 < n) pe2 = lst[tid + 512];
    if (tid +  768 < n) pe3 = lst[tid + 768];
    __syncthreads();

    // ---- horizontal scan: 80 rows x 2 halves of 40, in registers ----
    if (tid < 160) {
        int row = tid >> 1, half = tid & 1;
        float4* base = (float4*)S + row * 21 + half * 10;
        float v[40];
        #pragma unroll
        for (int q = 0; q < 10; ++q) {
            float4 t = base[q];
            v[4*q+0] = t.x; v[4*q+1] = t.y; v[4*q+2] = t.z; v[4*q+3] = t.w;
        }
        float run = 0.0f;
        #pragma unroll
        for (int j = 0; j < 40; ++j) { run += v[j]; v[j] = run; }
        float other = __shfl_xor(run, 1);            // partner half's total
        if (half) {
            #pragma unroll
            for (int j = 0; j < 40; ++j) v[j] += other;
        }
        #pragma unroll
        for (int q = 0; q < 10; ++q)
            base[q] = make_float4(v[4*q+0], v[4*q+1], v[4*q+2], v[4*q+3]);
    }
    __syncthreads();

    // ---- vertical scan: 20 col-groups x 8 chunks of 10 rows ----
    if (tid < 160) {
        int cg = tid >> 3;                 // 0..19 (cols cg*4..cg*4+3)
        int ch = tid & 7;                  // 0..7  (rows ch*10..ch*10+9)
        float4* col = (float4*)S + cg;
        float4 v[10];
        float4 run = make_float4(0.f, 0.f, 0.f, 0.f);
        #pragma unroll
        for (int j = 0; j < 10; ++j) {
            run = f4_add(run, col[(ch * 10 + j) * 21]);
            v[j] = run;
        }
        float4 incl = run;
        #pragma unroll
        for (int d = 1; d < 8; d <<= 1) {
            float4 u;
            u.x = __shfl_up(incl.x, d, 8);
            u.y = __shfl_up(incl.y, d, 8);
            u.z = __shfl_up(incl.z, d, 8);
            u.w = __shfl_up(incl.w, d, 8);
            if ((tid & 7) >= d) incl = f4_add(incl, u);
        }
        float4 off = make_float4(incl.x - run.x, incl.y - run.y,
                                 incl.z - run.z, incl.w - run.w);
        #pragma unroll
        for (int j = 0; j < 10; ++j)
            col[(ch * 10 + j) * 21] = f4_add(v[j], off);
    }
    __syncthreads();

    // ---- pool from LDS SAT: decode packed metadata (bit-exact) ----
    int ph = (c / P_) % P_;                // block-uniform
    int pw = c % P_;

    auto process = [&](uint2 e) {
        float x1 = (float)(e.y & 0xFFu);            // == rintf(bx[1])
        float y1 = (float)((e.y >> 8) & 0xFFu);
        int   mw = (int)((e.y >> 16) & 0xFFu);
        int   mh = (int)(e.y >> 24);
        float roi_w = mw ? (float)mw : 0.1f;        // == fmaxf(x2-x1, 0.1f)
        float roi_h = mh ? (float)mh : 0.1f;

        // ---- R10-frozen edge arithmetic ----
        const float RCP7 = __uint_as_float(0x3E124925u); // fl32(1/7)
        float bin_w = roi_w * RCP7;
        float bin_h = roi_h * RCP7;
        asm volatile("" : "+v"(bin_w), "+v"(bin_h));

        float hs_f = floorf(sep_ma((float)ph,       bin_h, y1));
        float he_f = ceilf (sep_ma((float)(ph + 1), bin_h, y1));
        float ws_f = floorf(sep_ma((float)pw,       bin_w, x1));
        float we_f = ceilf (sep_ma((float)(pw + 1), bin_w, x1));

        int hs = (int)fminf(fmaxf(hs_f, 0.0f), 80.0f);
        int he = (int)fminf(fmaxf(he_f, 0.0f), 80.0f);
        int ws = (int)fminf(fmaxf(ws_f, 0.0f), 80.0f);
        int we = (int)fminf(fmaxf(we_f, 0.0f), 80.0f);

        // SAT taps with implicit zero row/col (clamp + select)
        int i1 = he > 0 ? he - 1 : 0, i0 = hs > 0 ? hs - 1 : 0;
        int j1 = we > 0 ? we - 1 : 0, j0 = ws > 0 ? ws - 1 : 0;
        float v11 = S[i1 * SROW + j1];
        float v01 = S[i0 * SROW + j1];
        float v10 = S[i1 * SROW + j0];
        float v00 = S[i0 * SROW + j0];
        float t11 = (he > 0 && we > 0) ? v11 : 0.0f;
        float t01 = (hs > 0 && we > 0) ? v01 : 0.0f;
        float t10 = (he > 0 && ws > 0) ? v10 : 0.0f;
        float t00 = (hs > 0 && ws > 0) ? v00 : 0.0f;
        float bin_sum = ((t11 - t01) - t10) + t00;   // ref op order

        int area = (he - hs) * (we - ws);
        out[(size_t)e.x * C_ + c] = (area > 0) ? bin_sum / (float)area : 0.0f;
    };

    if (tid        < n) process(pe0);
    if (tid +  256 < n) process(pe1);
    if (tid +  512 < n) process(pe2);
    if (tid +  768 < n) process(pe3);
    for (int i = tid + 1024; i < n; i += 256) process(lst[i]);
}

// ---- fallback: R11 direct-sum kernel (ws too small) ----
__global__ __launch_bounds__(256) void psroi_direct_kernel(
    const float* __restrict__ fsam,
    const float* __restrict__ box,
    float* __restrict__ out)
{
    int id = blockIdx.x;
    int j  = id & 7;
    int m  = id >> 3;
    int g  = (m < 512) ? j : j + 8;
    int l  = (m < 512) ? m : m - 512;
    int c    = g * 16 + (l >> 5);
    int rblk = l & 31;
    if (c >= C_) return;

    int r = rblk * 256 + (int)threadIdx.x;
    int pw = c % P_;
    int ph = (c / P_) % P_;

    const float* bx = box + (size_t)r * 5;
    int   b  = (int)bx[0];
    float x1 = rintf(bx[1]);
    float y1 = rintf(bx[2]);
    float x2 = rintf(bx[3] + 1.0f);
    float y2 = rintf(bx[4] + 1.0f);

    float roi_w = fmaxf(x2 - x1, 0.1f);
    float roi_h = fmaxf(y2 - y1, 0.1f);

    const float RCP7 = __uint_as_float(0x3E124925u);
    float bin_w = roi_w * RCP7;
    float bin_h = roi_h * RCP7;
    asm volatile("" : "+v"(bin_w), "+v"(bin_h));

    float hs_f = floorf(sep_ma((float)ph,       bin_h, y1));
    float he_f = ceilf (sep_ma((float)(ph + 1), bin_h, y1));
    float ws_f = floorf(sep_ma((float)pw,       bin_w, x1));
    float we_f = ceilf (sep_ma((float)(pw + 1), bin_w, x1));

    int hs = (int)fminf(fmaxf(hs_f, 0.0f), 80.0f);
    int he = (int)fminf(fmaxf(he_f, 0.0f), 80.0f);
    int ws = (int)fminf(fmaxf(ws_f, 0.0f), 80.0f);
    int we = (int)fminf(fmaxf(we_f, 0.0f), 80.0f);

    const float* plane = fsam + ((size_t)b * C_ + c) * (H_ * W_);
    float s = 0.0f;
    for (int y = hs; y < he; ++y) {
        const float* row = plane + y * W_;
        for (int x = ws; x < we; ++x) s += row[x];
    }
    int area = (he - hs) * (we - ws);
    out[(size_t)r * C_ + c] = (area > 0) ? s / (float)area : 0.0f;
}

extern "C" void kernel_launch(void* const* d_in, const int* in_sizes, int n_in,
                              void* d_out, int out_size, void* d_ws, size_t ws_size,
                              hipStream_t stream) {
    const float* fsam = (const float*)d_in[0];
    const float* box  = (const float*)d_in[1];
    float* out = (float*)d_out;

    // ws layout: [0,32) counts (8 ints), [32, 32+8*8192*8) packed buckets
    size_t need = 32 + (size_t)N_ * R_ * sizeof(uint2);   // ~512 KB
    if (ws_size >= need) {
        int*   cnt     = (int*)d_ws;
        uint2* buckets = (uint2*)((char*)d_ws + 32);
        bucket_kernel<<<N_, 256, 0, stream>>>(box, cnt, buckets);
        fused_kernel<<<N_ * C_, 256, 0, stream>>>(fsam, cnt, buckets, out);
    } else {
        psroi_direct_kernel<<<8192, 256, 0, stream>>>(fsam, box, out);
    }
}

// Round 17
// 37.509 us; speedup vs baseline: 1.1295x; 1.1295x over previous
//
#include <hip/hip_runtime.h>

// PSROI pooling: fsam (N=8, C=245, H=80, W=80) f32, box (R=8192, 5) f32
// out (R, 245) f32. out[r, c] = mean over fsam[b, c, hs:he, ws:we].
//
// ARITHMETIC (frozen since R10, DO NOT TOUCH): bin = roi * fl32(1/7)
// (reciprocal multiply, 0x3E124925) and edges = SEPARATELY-rounded
// g*bin + off (asm barriers). Matches ref (absmax <= 0.016 << 0.0725).
//
// R17: R15 base (R16's bundled changes all reverted - they regressed) with
// ONE change: 512-thread blocks + finer scan chunks. R13/R15 evidence says
// fused is STALL-dominated (issue-count model predicts ~6us/CU, measured
// ~33us; occupancy ~3 blocks/CU; VALUBusy 16%): per-block serial latency
// (barriers, 40-add chains, 160/256 active threads) is exposed. 512
// threads at the SAME 26.9KB LDS doubles resident waves/CU and halves
// every dependent chain: h-scan 80 rows x 4 chunks of 20 (width-4 shfl
// scan), v-scan 20 colgroups x 16 chunks of 5 (width-16 shfl scan),
// pool 2 iters. Scan reassociation drift stays ~1e-2 (9x headroom).

#define N_ 8
#define C_ 245
#define H_ 80
#define W_ 80
#define R_ 8192
#define P_ 7
#define SROW 84                    // row stride in floats (21 float4)

// XLA-style separately-rounded a*b + c in f32; barriers forbid contraction.
__device__ __forceinline__ float sep_ma(float a, float b, float c) {
    float p = a * b;                 // v_mul_f32, IEEE RN
    asm volatile("" : "+v"(p));      // contraction barrier
    float s = p + c;                 // v_add_f32, IEEE RN
    asm volatile("" : "+v"(s));
    return s;
}

// ---- kernel 1: deterministic bucket build (8 blocks, no atomics) ----
__global__ __launch_bounds__(256) void bucket_kernel(
    const float* __restrict__ box, int* __restrict__ cnt,
    int* __restrict__ buckets)
{
    __shared__ int psum[256];
    int b = blockIdx.x;                    // image
    int t = threadIdx.x;
    int r0 = t * 32;                       // contiguous range per thread

    unsigned match = 0u;
    int m = 0;
    #pragma unroll
    for (int k = 0; k < 32; ++k) {
        int bb = (int)box[(size_t)(r0 + k) * 5];
        if (bb == b) { match |= 1u << k; ++m; }
    }
    psum[t] = m;
    __syncthreads();

    // Hillis-Steele inclusive scan over 256 counts
    for (int off = 1; off < 256; off <<= 1) {
        int v = (t >= off) ? psum[t - off] : 0;
        __syncthreads();
        psum[t] += v;
        __syncthreads();
    }
    int pos = psum[t] - m;                 // exclusive prefix
    for (int k = 0; k < 32; ++k)
        if (match & (1u << k)) buckets[b * R_ + pos++] = r0 + k;
    if (t == 255) cnt[b] = psum[255];
}

__device__ __forceinline__ float4 f4_add(float4 a, float4 b) {
    return make_float4(a.x + b.x, a.y + b.y, a.z + b.z, a.w + b.w);
}

// ---- kernel 2: fused SAT-in-LDS + pool, 512 threads ----
__global__ __launch_bounds__(512) void fused_kernel(
    const float* __restrict__ fsam,
    const float* __restrict__ box,
    const int* __restrict__ cnt,
    const int* __restrict__ buckets,
    float* __restrict__ out)
{
    __shared__ float S[H_ * SROW];         // 26880 B, rows 16B-aligned
    int id  = blockIdx.x;                  // 0..1959
    int b   = id & 7;                      // image (XCD swizzle: XCD = b)
    int c   = id >> 3;                     // channel 0..244
    int tid = threadIdx.x;

    const float* plane = fsam + ((size_t)b * C_ + c) * (H_ * W_);

    // ---- load: 1600 float4, coalesced global -> b128 LDS ----
    for (int i = tid; i < 1600; i += 512) {
        int row = (int)((unsigned)i / 20u);
        int c4  = i - row * 20;
        float4 v = ((const float4*)plane)[i];
        ((float4*)S)[row * 21 + c4] = v;
    }
    __syncthreads();

    // ---- horizontal scan: 80 rows x 4 chunks of 20, in registers ----
    if (tid < 320) {
        int row = tid >> 2, q = tid & 3;   // chunk q covers cols q*20..q*20+19
        float4* base = (float4*)S + row * 21 + q * 5;
        float v[20];
        #pragma unroll
        for (int k = 0; k < 5; ++k) {
            float4 t = base[k];
            v[4*k+0] = t.x; v[4*k+1] = t.y; v[4*k+2] = t.z; v[4*k+3] = t.w;
        }
        float run = 0.0f;
        #pragma unroll
        for (int j = 0; j < 20; ++j) { run += v[j]; v[j] = run; }
        // segmented inclusive scan of chunk totals across 4 lanes (quad)
        float incl = run;
        #pragma unroll
        for (int d = 1; d < 4; d <<= 1) {
            float u = __shfl_up(incl, d, 4);
            if (q >= d) incl += u;
        }
        float off = incl - run;            // exclusive prefix for this chunk
        #pragma unroll
        for (int j = 0; j < 20; ++j) v[j] += off;
        #pragma unroll
        for (int k = 0; k < 5; ++k)
            base[k] = make_float4(v[4*k+0], v[4*k+1], v[4*k+2], v[4*k+3]);
    }
    __syncthreads();

    // ---- vertical scan: 20 col-groups x 16 chunks of 5 rows ----
    if (tid < 320) {
        int cg = tid >> 4;                 // 0..19 (cols cg*4..cg*4+3)
        int ch = tid & 15;                 // 0..15 (rows ch*5..ch*5+4)
        float4* col = (float4*)S + cg;
        float4 v[5];
        float4 run = make_float4(0.f, 0.f, 0.f, 0.f);
        #pragma unroll
        for (int j = 0; j < 5; ++j) {
            run = f4_add(run, col[(ch * 5 + j) * 21]);
            v[j] = run;
        }
        // segmented inclusive scan of chunk totals across 16 lanes
        float4 incl = run;
        #pragma unroll
        for (int d = 1; d < 16; d <<= 1) {
            float4 u;
            u.x = __shfl_up(incl.x, d, 16);
            u.y = __shfl_up(incl.y, d, 16);
            u.z = __shfl_up(incl.z, d, 16);
            u.w = __shfl_up(incl.w, d, 16);
            if (ch >= d) incl = f4_add(incl, u);
        }
        float4 off = make_float4(incl.x - run.x, incl.y - run.y,
                                 incl.z - run.z, incl.w - run.w);
        #pragma unroll
        for (int j = 0; j < 5; ++j)
            col[(ch * 5 + j) * 21] = f4_add(v[j], off);
    }
    __syncthreads();

    // ---- pool this image's ROIs from the LDS SAT (R15 body) ----
    int ph = (c / P_) % P_;                // block-uniform
    int pw = c % P_;
    int n  = cnt[b];
    const int* lst = buckets + b * R_;

    for (int i = tid; i < n; i += 512) {
        int r = lst[i];
        const float* bx = box + (size_t)r * 5;

        // ---- R10-frozen edge arithmetic ----
        float x1 = rintf(bx[1]);
        float y1 = rintf(bx[2]);
        float x2 = rintf(bx[3] + 1.0f);
        float y2 = rintf(bx[4] + 1.0f);

        float roi_w = fmaxf(x2 - x1, 0.1f);
        float roi_h = fmaxf(y2 - y1, 0.1f);

        const float RCP7 = __uint_as_float(0x3E124925u); // fl32(1/7)
        float bin_w = roi_w * RCP7;
        float bin_h = roi_h * RCP7;
        asm volatile("" : "+v"(bin_w), "+v"(bin_h));

        float hs_f = floorf(sep_ma((float)ph,       bin_h, y1));
        float he_f = ceilf (sep_ma((float)(ph + 1), bin_h, y1));
        float ws_f = floorf(sep_ma((float)pw,       bin_w, x1));
        float we_f = ceilf (sep_ma((float)(pw + 1), bin_w, x1));

        int hs = (int)fminf(fmaxf(hs_f, 0.0f), 80.0f);
        int he = (int)fminf(fmaxf(he_f, 0.0f), 80.0f);
        int ws = (int)fminf(fmaxf(ws_f, 0.0f), 80.0f);
        int we = (int)fminf(fmaxf(we_f, 0.0f), 80.0f);

        // SAT taps with implicit zero row/col (clamp + select)
        int i1 = he > 0 ? he - 1 : 0, i0 = hs > 0 ? hs - 1 : 0;
        int j1 = we > 0 ? we - 1 : 0, j0 = ws > 0 ? ws - 1 : 0;
        float v11 = S[i1 * SROW + j1];
        float v01 = S[i0 * SROW + j1];
        float v10 = S[i1 * SROW + j0];
        float v00 = S[i0 * SROW + j0];
        float t11 = (he > 0 && we > 0) ? v11 : 0.0f;
        float t01 = (hs > 0 && we > 0) ? v01 : 0.0f;
        float t10 = (he > 0 && ws > 0) ? v10 : 0.0f;
        float t00 = (hs > 0 && ws > 0) ? v00 : 0.0f;
        float bin_sum = ((t11 - t01) - t10) + t00;   // ref op order

        int area = (he - hs) * (we - ws);
        out[(size_t)r * C_ + c] = (area > 0) ? bin_sum / (float)area : 0.0f;
    }
}

// ---- fallback: R11 direct-sum kernel (ws too small) ----
__global__ __launch_bounds__(256) void psroi_direct_kernel(
    const float* __restrict__ fsam,
    const float* __restrict__ box,
    float* __restrict__ out)
{
    int id = blockIdx.x;
    int j  = id & 7;
    int m  = id >> 3;
    int g  = (m < 512) ? j : j + 8;
    int l  = (m < 512) ? m : m - 512;
    int c    = g * 16 + (l >> 5);
    int rblk = l & 31;
    if (c >= C_) return;

    int r = rblk * 256 + (int)threadIdx.x;
    int pw = c % P_;
    int ph = (c / P_) % P_;

    const float* bx = box + (size_t)r * 5;
    int   b  = (int)bx[0];
    float x1 = rintf(bx[1]);
    float y1 = rintf(bx[2]);
    float x2 = rintf(bx[3] + 1.0f);
    float y2 = rintf(bx[4] + 1.0f);

    float roi_w = fmaxf(x2 - x1, 0.1f);
    float roi_h = fmaxf(y2 - y1, 0.1f);

    const float RCP7 = __uint_as_float(0x3E124925u);
    float bin_w = roi_w * RCP7;
    float bin_h = roi_h * RCP7;
    asm volatile("" : "+v"(bin_w), "+v"(bin_h));

    float hs_f = floorf(sep_ma((float)ph,       bin_h, y1));
    float he_f = ceilf (sep_ma((float)(ph + 1), bin_h, y1));
    float ws_f = floorf(sep_ma((float)pw,       bin_w, x1));
    float we_f = ceilf (sep_ma((float)(pw + 1), bin_w, x1));

    int hs = (int)fminf(fmaxf(hs_f, 0.0f), 80.0f);
    int he = (int)fminf(fmaxf(he_f, 0.0f), 80.0f);
    int ws = (int)fminf(fmaxf(ws_f, 0.0f), 80.0f);
    int we = (int)fminf(fmaxf(we_f, 0.0f), 80.0f);

    const float* plane = fsam + ((size_t)b * C_ + c) * (H_ * W_);
    float s = 0.0f;
    for (int y = hs; y < he; ++y) {
        const float* row = plane + y * W_;
        for (int x = ws; x < we; ++x) s += row[x];
    }
    int area = (he - hs) * (we - ws);
    out[(size_t)r * C_ + c] = (area > 0) ? s / (float)area : 0.0f;
}

extern "C" void kernel_launch(void* const* d_in, const int* in_sizes, int n_in,
                              void* d_out, int out_size, void* d_ws, size_t ws_size,
                              hipStream_t stream) {
    const float* fsam = (const float*)d_in[0];
    const float* box  = (const float*)d_in[1];
    float* out = (float*)d_out;

    // ws layout: [0,32) counts (8 ints), [32, 32+8*8192*4) buckets
    size_t need = 32 + (size_t)N_ * R_ * sizeof(int);   // 262176 B
    if (ws_size >= need) {
        int* cnt     = (int*)d_ws;
        int* buckets = (int*)((char*)d_ws + 32);
        bucket_kernel<<<N_, 256, 0, stream>>>(box, cnt, buckets);
        fused_kernel<<<N_ * C_, 512, 0, stream>>>(fsam, box, cnt, buckets, out);
    } else {
        psroi_direct_kernel<<<8192, 256, 0, stream>>>(fsam, box, out);
    }
}